// Round 2
// baseline (633.185 us; speedup 1.0000x reference)
//
#include <hip/hip_runtime.h>
#include <cmath>

#define EPSC 1e-5f
typedef unsigned short ushortT;
typedef unsigned int uintT;
typedef __attribute__((ext_vector_type(8))) short bf16x8;
typedef __attribute__((ext_vector_type(4))) float f32x4;

// ---------------- output layout (floats) ----------------
constexpr size_t O_SEG   = 0;          // 32*2*240*240 = 3686400
constexpr size_t O_GL    = 3686400;    // 64
constexpr size_t O_LOGIT = 3686464;    // 32
constexpr size_t O_PROB  = 3686496;    // 32
constexpr size_t O_PATCH = 3686528;    // 115200
constexpr size_t O_RES   = 3801728;    // 7200
constexpr size_t O_CTX   = 3808928;    // 5529600
constexpr size_t O_ALN   = 9338528;    // 5529600
constexpr size_t O_IDX   = 14868128;   // 7200

// ---------------- ws layout (float elements) ----------------
constexpr size_t WS_MS64 = 0;                    // 7200 doubles = 14400 floats
constexpr size_t WS_AVG  = 14400;                // 24576
constexpr size_t CB      = 38976;
constexpr size_t WS_QPK  = CB;
constexpr size_t WS_TOP2G= CB + 5898240;
constexpr size_t WS_CPH  = CB;
constexpr size_t WS_CPL  = CB + 3551232;
constexpr size_t WS_WPK  = CB + 7102464;
constexpr size_t WS_H1   = CB + 8000000;
constexpr size_t WS_T1H  = CB;                   // 2,097,152 floats (bf16 x2)
constexpr size_t WS_T1L  = CB + 2097152;
constexpr size_t WS_H2   = CB + 4200000;
constexpr size_t WS_WPK2 = CB + 8950000;
constexpr size_t WS_LOW  = CB;

// =======================================================================
// Pack Q -> bf16 hi in MFMA-fragment order (blocks < 2880), and pack
// W1/W2 -> bf16 hi/lo (blocks >= 2880). Merged to save a dispatch.
__global__ __launch_bounds__(256) void k_qpackW(const float* __restrict__ Q,
    const float* __restrict__ w1, const float* __restrict__ w2,
    ushortT* __restrict__ qpk, ushortT* __restrict__ wpk,
    ushortT* __restrict__ wpk2) {
  int bid = blockIdx.x;
  if (bid < 2880) {
    int id = bid * 256 + threadIdx.x;
    int r = id & 15;
    int g = (id >> 4) & 3;
    int rest = id >> 6;
    int sub = rest % 15;
    int bkc = rest / 15;
    int kc = bkc % 24, b = bkc / 24;
    if (b >= 32) return;
    int q = sub * 16 + r;
    int k0 = kc * 32 + g * 8;
    float x[8];
    if (q < 225) {
      const float* src = Q + ((size_t)(b * 225 + q)) * 768 + k0;
#pragma unroll
      for (int e = 0; e < 8; ++e) x[e] = src[e];
    } else {
#pragma unroll
      for (int e = 0; e < 8; ++e) x[e] = 0.f;
    }
    uintT hb[8];
#pragma unroll
    for (int e = 0; e < 8; ++e) hb[e] = __float_as_uint(x[e]);
    uint4 hv;
    hv.x = (hb[0] >> 16) | (hb[1] & 0xFFFF0000u);
    hv.y = (hb[2] >> 16) | (hb[3] & 0xFFFF0000u);
    hv.z = (hb[4] >> 16) | (hb[5] & 0xFFFF0000u);
    hv.w = (hb[6] >> 16) | (hb[7] & 0xFFFF0000u);
    size_t base = ((size_t)(b * 24 + kc) * 30 + sub) * 512 + (g * 16 + r) * 8;
    *(uint4*)(qpk + base) = hv;
    return;
  }
  int id = (bid - 2880) * 256 + threadIdx.x;
  if (id < 110592) {
    int ccq = id & 3;
    int o = (id >> 2) & 127;
    int pc = id >> 9;
    ushortT hu[8], lu[8];
#pragma unroll
    for (int e = 0; e < 8; ++e) {
      int c = (pc % 24) * 32 + ccq * 8 + e;
      float x = w1[((size_t)o * 768 + c) * 9 + pc / 24];
      uintT bits = __float_as_uint(x);
      float lo = x - __uint_as_float(bits & 0xFFFF0000u);
      hu[e] = (ushortT)(bits >> 16);
      lu[e] = (ushortT)(__float_as_uint(lo) >> 16);
    }
    uint4 h, lw;
    h.x = (uintT)hu[0] | ((uintT)hu[1] << 16);
    h.y = (uintT)hu[2] | ((uintT)hu[3] << 16);
    h.z = (uintT)hu[4] | ((uintT)hu[5] << 16);
    h.w = (uintT)hu[6] | ((uintT)hu[7] << 16);
    lw.x = (uintT)lu[0] | ((uintT)lu[1] << 16);
    lw.y = (uintT)lu[2] | ((uintT)lu[3] << 16);
    lw.z = (uintT)lu[4] | ((uintT)lu[5] << 16);
    lw.w = (uintT)lu[6] | ((uintT)lu[7] << 16);
    size_t base = (((size_t)pc) * 128 + o) * 32 + ccq * 8;
    *(uint4*)(wpk + base) = h;
    *(uint4*)(wpk + 884736 + base) = lw;
  } else {
    int id2 = id - 110592;
    if (id2 >= 9216) return;
    int ccq = id2 & 3;
    int o = (id2 >> 2) & 63;
    int pc = id2 >> 8;                          // pos*4+ch, 0..35
    int pos = pc >> 2, ch = pc & 3;
    ushortT hu[8], lu[8];
#pragma unroll
    for (int e = 0; e < 8; ++e) {
      int c = ch * 32 + ccq * 8 + e;
      float x = w2[((size_t)o * 128 + c) * 9 + pos];
      uintT bits = __float_as_uint(x);
      float lo = x - __uint_as_float(bits & 0xFFFF0000u);
      hu[e] = (ushortT)(bits >> 16);
      lu[e] = (ushortT)(__float_as_uint(lo) >> 16);
    }
    uint4 h, lw;
    h.x = (uintT)hu[0] | ((uintT)hu[1] << 16);
    h.y = (uintT)hu[2] | ((uintT)hu[3] << 16);
    h.z = (uintT)hu[4] | ((uintT)hu[5] << 16);
    h.w = (uintT)hu[6] | ((uintT)hu[7] << 16);
    lw.x = (uintT)lu[0] | ((uintT)lu[1] << 16);
    lw.y = (uintT)lu[2] | ((uintT)lu[3] << 16);
    lw.z = (uintT)lu[4] | ((uintT)lu[5] << 16);
    lw.w = (uintT)lu[6] | ((uintT)lu[7] << 16);
    size_t base = (((size_t)pc) * 64 + o) * 32 + ccq * 8;
    *(uint4*)(wpk2 + base) = h;
    *(uint4*)(wpk2 + 73728 + base) = lw;
  }
}

// =======================================================================
// MFMA sim scan: hi-only bf16 candidate generation. grid(sp=64, b=32).
__global__ __launch_bounds__(256, 3) void k_simm(const ushortT* __restrict__ qpk,
    const float* __restrict__ PM, float4* __restrict__ top2g) {
  __shared__ ushortT sP[2 * 2048];   // [buf][subs 0-3 hi][512]
  __shared__ float4 smrg[240];
  __shared__ float srp[64];
  int sp = blockIdx.x, b = blockIdx.y;
  int t = threadIdx.x;
  int w = t >> 6, l = t & 63;
  int mq = t >> 3, kq = t & 7;
  const int sub0 = w * 4;
  const ushortT* qB0 = qpk + (size_t)(b * 24) * 30 * 512;

#define LOADQ(KC)                                                             \
  {                                                                           \
    const ushortT* qk = qB0 + (size_t)(KC) * (30 * 512);                      \
    _Pragma("unroll")                                                         \
    for (int ss = 0; ss < 4; ++ss) {                                          \
      int subc = sub0 + ss; if (subc > 14) subc = 14;                         \
      qh[ss] = *(const bf16x8*)(qk + subc * 512 + l * 8);                     \
    }                                                                         \
  }

#define LOADP(PR, KC)                                                         \
  {                                                                           \
    _Pragma("unroll")                                                         \
    for (int pass = 0; pass < 2; ++pass) {                                    \
      int ml = mq + pass * 32;                                                \
      PR[pass] = *(const float4*)(pmBase + (size_t)ml * 768 + (KC) * 32 + kq * 4); \
    }                                                                         \
  }

#define CVTW(PR, BUF)                                                         \
  {                                                                           \
    _Pragma("unroll")                                                         \
    for (int pass = 0; pass < 2; ++pass) {                                    \
      int ml = mq + pass * 32;                                                \
      float4 x = PR[pass];                                                    \
      pn[pass] += x.x * x.x + x.y * x.y + x.z * x.z + x.w * x.w;              \
      uintT a0 = __float_as_uint(x.x), a1 = __float_as_uint(x.y);             \
      uintT a2 = __float_as_uint(x.z), a3 = __float_as_uint(x.w);             \
      uintT h01 = (a0 >> 16) | (a1 & 0xFFFF0000u);                            \
      uintT h23 = (a2 >> 16) | (a3 & 0xFFFF0000u);                            \
      int off = (ml >> 4) * 512 + (kq >> 1) * 128 + (ml & 15) * 8 + (kq & 1) * 4; \
      *(uint2*)(&sP[(BUF) + off]) = make_uint2(h01, h23);                     \
    }                                                                         \
  }

#define MFMAPH(BUF)                                                           \
  {                                                                           \
    bf16x8 bh[4];                                                             \
    _Pragma("unroll")                                                         \
    for (int mm = 0; mm < 4; ++mm)                                            \
      bh[mm] = *(const bf16x8*)&sP[(BUF) + mm * 512 + l * 8];                 \
    _Pragma("unroll")                                                         \
    for (int ss = 0; ss < 4; ++ss) {                                          \
      if (sub0 + ss < 15) {                                                   \
        _Pragma("unroll")                                                     \
        for (int mm = 0; mm < 4; ++mm) {                                      \
          acc[ss][mm] = __builtin_amdgcn_mfma_f32_16x16x32_bf16(              \
              qh[ss], bh[mm], acc[ss][mm], 0, 0, 0);                          \
        }                                                                     \
      }                                                                       \
    }                                                                         \
  }

  f32x4 acc[4][4];
#pragma unroll
  for (int ss = 0; ss < 4; ++ss)
#pragma unroll
    for (int mm = 0; mm < 4; ++mm) acc[ss][mm] = (f32x4){0.f, 0.f, 0.f, 0.f};
  float pn[2] = {0.f, 0.f};
  const int mbase = sp * 64;
  const float* pmBase = PM + ((size_t)b * 4096 + mbase) * 768;

  bf16x8 qh[4];
  float4 pr[2];

  LOADP(pr, 0);
  CVTW(pr, 0);
  __syncthreads();

  for (int kc2 = 0; kc2 < 12; ++kc2) {
    int kc = kc2 * 2;
    LOADQ(kc);
    LOADP(pr, kc + 1);
    MFMAPH(0);
    CVTW(pr, 2048);
    __syncthreads();
    LOADQ(kc + 1);
    if (kc2 < 11) {
      LOADP(pr, kc + 2);
    }
    MFMAPH(2048);
    if (kc2 < 11) {
      CVTW(pr, 0);
    }
    __syncthreads();
  }

#pragma unroll
  for (int pass = 0; pass < 2; ++pass) {
    float v = pn[pass];
    v += __shfl_xor(v, 1); v += __shfl_xor(v, 2); v += __shfl_xor(v, 4);
    if (kq == 0) srp[mq + pass * 32] = 1.0f / fmaxf(sqrtf(v), 1e-12f);
  }
  __syncthreads();
  float rpv_[4];
#pragma unroll
  for (int mf = 0; mf < 4; ++mf) rpv_[mf] = srp[mf * 16 + (l & 15)];
#pragma unroll
  for (int ss = 0; ss < 4; ++ss) {
    int sub = sub0 + ss;
    if (sub >= 15) break;
#pragma unroll
    for (int j = 0; j < 4; ++j) {
      float a1 = -1e30f, a2 = -1e30f; int ai1 = -1, ai2 = -1;
#pragma unroll
      for (int mf = 0; mf < 4; ++mf) {
        float v = acc[ss][mf][j] * rpv_[mf];
        int mi = mbase + mf * 16 + (l & 15);
        if (v > a1) { a2 = a1; ai2 = ai1; a1 = v; ai1 = mi; }
        else if (v > a2) { a2 = v; ai2 = mi; }
      }
#pragma unroll
      for (int o = 1; o <= 8; o <<= 1) {
        float b1 = __shfl_xor(a1, o), b2 = __shfl_xor(a2, o);
        int bi1 = __shfl_xor(ai1, o), bi2 = __shfl_xor(ai2, o);
        if (b1 > a1) {
          float n2; int ni2;
          if (a1 > b2) { n2 = a1; ni2 = ai1; } else { n2 = b2; ni2 = bi2; }
          a1 = b1; ai1 = bi1; a2 = n2; ai2 = ni2;
        } else {
          if (b1 > a2) { a2 = b1; ai2 = bi1; }
        }
      }
      if ((l & 15) == j) {
        int row = sub * 16 + (l >> 4) * 4 + j;
        smrg[row] = make_float4(a1, a2, __int_as_float(ai1), __int_as_float(ai2));
      }
    }
  }
  __syncthreads();
  if (t < 240) top2g[((size_t)(b * 240 + t)) * 64 + sp] = smrg[t];
#undef LOADQ
#undef LOADP
#undef CVTW
#undef MFMAPH
}

// =======================================================================
// refine: gather 128 candidates, approx-top8, f64 rescore (batched 2x4
// for ILP). Arithmetic order per candidate is bit-identical to serial.
__global__ __launch_bounds__(256) void k_refine(const float* __restrict__ Q,
    const float* __restrict__ PM, const float4* __restrict__ top2g,
    float* __restrict__ oIdx, float* __restrict__ oRes,
    float* __restrict__ oCtx, float* __restrict__ oAln,
    double* __restrict__ ms64) {
  int wid = (blockIdx.x * 256 + threadIdx.x) >> 6;
  int lane = threadIdx.x & 63;
  if (wid >= 7200) return;
  int b = wid / 225, pr = wid % 225;
  float4 e = top2g[((size_t)(b * 240 + pr)) * 64 + lane];
  float v1 = e.x, v2 = e.y;
  int i1 = __float_as_int(e.z), i2 = __float_as_int(e.w);
  int cand[8];
#pragma unroll
  for (int k = 0; k < 8; ++k) {
    float v = v1; int mi = i1;
    if (v2 > v || (v2 == v && (uintT)i2 < (uintT)mi)) { v = v2; mi = i2; }
#pragma unroll
    for (int o = 1; o <= 32; o <<= 1) {
      float ov = __shfl_xor(v, o); int omi = __shfl_xor(mi, o);
      if (ov > v || (ov == v && (uintT)omi < (uintT)mi)) { v = ov; mi = omi; }
    }
    cand[k] = mi;
    if (i1 == mi) v1 = -3e38f;
    if (i2 == mi) v2 = -3e38f;
  }
  const float* qr = Q + ((size_t)b * 225 + pr) * 768;
  float qv[12]; double nq = 0.0;
#pragma unroll
  for (int j = 0; j < 12; ++j) { float x = qr[lane + 64 * j]; qv[j] = x; nq += (double)x * (double)x; }
#pragma unroll
  for (int o = 1; o < 64; o <<= 1) nq += __shfl_xor(nq, o);
  double qn = fmax(sqrt(nq), 1e-12);
  double best = -1e300; int bi = 0;
#pragma unroll
  for (int pass = 0; pass < 2; ++pass) {
    const float* pp[4];
    double d[4], nn[4];
#pragma unroll
    for (int c = 0; c < 4; ++c) {
      pp[c] = PM + ((size_t)b * 4096 + cand[pass * 4 + c]) * 768 + lane;
      d[c] = 0.0; nn[c] = 0.0;
    }
#pragma unroll
    for (int j = 0; j < 12; ++j) {
#pragma unroll
      for (int c = 0; c < 4; ++c) {
        double pe = (double)pp[c][64 * j];
        d[c] += (double)qv[j] * pe;
        nn[c] += pe * pe;
      }
    }
#pragma unroll
    for (int o = 1; o < 64; o <<= 1) {
#pragma unroll
      for (int c = 0; c < 4; ++c) {
        d[c] += __shfl_xor(d[c], o);
        nn[c] += __shfl_xor(nn[c], o);
      }
    }
#pragma unroll
    for (int c = 0; c < 4; ++c) {
      int mi = cand[pass * 4 + c];
      double s = d[c] / (qn * fmax(sqrt(nn[c]), 1e-12));
      if (s > best || (s == best && mi < bi)) { best = s; bi = mi; }
    }
  }
  if (lane == 0) {
    oIdx[wid] = (float)bi;
    oRes[wid] = (float)(0.5 * (1.0 - best));
    ms64[wid] = best;
  }
  const float* ar = PM + ((size_t)b * 4096 + bi) * 768;
  float* cw = oCtx + (size_t)wid * 768;
  float* aw = oAln + (size_t)wid * 768;
#pragma unroll
  for (int j = 0; j < 12; ++j) {
    float a = ar[lane + 64 * j];
    float qq = qv[j];
    aw[lane + 64 * j] = a;
    cw[lane + 64 * j] = qq + fabsf(qq - a);
  }
}

// =======================================================================
__global__ __launch_bounds__(256) void k_pool(const float* __restrict__ ctx,
                                              float* __restrict__ avg) {
  int b = blockIdx.x, c = blockIdx.y, t = threadIdx.x;
  int d = c * 256 + t;
  float s = 0.f;
  for (int p = 0; p < 225; ++p) s += ctx[((size_t)b * 225 + p) * 768 + d];
  avg[b * 768 + d] = s / 225.0f;
}

// =======================================================================
// global head: topk + pooled + 3-layer MLP, wave-parallel coalesced
// matvecs (lanes split K, butterfly reduce; was per-thread 3KB row
// streams with 16x overfetch and ~20us of unhidden latency).
__global__ __launch_bounds__(256) void k_head(const float* __restrict__ ctx,
    const double* __restrict__ ms64, const float* __restrict__ avg,
    const float* __restrict__ g1, const float* __restrict__ b1g, const float* __restrict__ b1b,
    const float* __restrict__ b1m, const float* __restrict__ b1v,
    const float* __restrict__ g2, const float* __restrict__ b2g, const float* __restrict__ b2b,
    const float* __restrict__ b2m, const float* __restrict__ b2v,
    const float* __restrict__ g3,
    float* __restrict__ oGl, float* __restrict__ oLogit, float* __restrict__ oProb) {
  __shared__ int tki[10];
  __shared__ float pooled[768];
  __shared__ float h1s[128];
  __shared__ float h2s[64];
  __shared__ float gls[2];
  int b = blockIdx.x, t = threadIdx.x;
  int w = t >> 6, l = t & 63;
  if (t < 64) {
    double rv[4]; int ri[4];
#pragma unroll
    for (int j = 0; j < 4; ++j) {
      int p = t + 64 * j; ri[j] = p;
      rv[j] = (p < 225) ? 0.5 * (1.0 - ms64[b * 225 + p]) : -1e300;
    }
    for (int k = 0; k < 10; ++k) {
      double bv = -1e301; int bI = 1 << 30;
#pragma unroll
      for (int j = 0; j < 4; ++j)
        if (rv[j] > bv || (rv[j] == bv && ri[j] < bI)) { bv = rv[j]; bI = ri[j]; }
#pragma unroll
      for (int o = 1; o < 64; o <<= 1) {
        double ov = __shfl_xor(bv, o); int oi = __shfl_xor(bI, o);
        if (ov > bv || (ov == bv && oi < bI)) { bv = ov; bI = oi; }
      }
      if (t == 0) tki[k] = bI;
#pragma unroll
      for (int j = 0; j < 4; ++j) if (ri[j] == bI) rv[j] = -1e300;
    }
  }
  __syncthreads();
#pragma unroll
  for (int di = 0; di < 3; ++di) {
    int d = t + di * 256;
    float s = 0.f;
    for (int k = 0; k < 10; ++k) s += ctx[((size_t)b * 225 + tki[k]) * 768 + d];
    pooled[d] = 0.5f * avg[b * 768 + d] + 0.5f * (s / 10.0f);
  }
  __syncthreads();
  // ---- layer 1: [128,768] matvec, 4 waves x 32 outputs, coalesced K ----
  {
    float pv[12];
#pragma unroll
    for (int j = 0; j < 12; ++j) pv[j] = pooled[l + 64 * j];
#pragma unroll
    for (int oo = 0; oo < 32; ++oo) {
      int o = w * 32 + oo;
      const float* gr = g1 + (size_t)o * 768;
      float a = 0.f;
#pragma unroll
      for (int j = 0; j < 12; ++j) a += pv[j] * gr[l + 64 * j];
#pragma unroll
      for (int off = 1; off < 64; off <<= 1) a += __shfl_xor(a, off);
      if (l == 0) {
        float sc = b1g[o] / sqrtf(b1v[o] + EPSC);
        h1s[o] = fmaxf((a - b1m[o]) * sc + b1b[o], 0.f);
      }
    }
  }
  __syncthreads();
  // ---- layer 2: [64,128] matvec, 4 waves x 16 outputs ----
  {
    float hv0 = h1s[l], hv1 = h1s[l + 64];
#pragma unroll
    for (int oo = 0; oo < 16; ++oo) {
      int o = w * 16 + oo;
      const float* gr = g2 + (size_t)o * 128;
      float a = hv0 * gr[l] + hv1 * gr[l + 64];
#pragma unroll
      for (int off = 1; off < 64; off <<= 1) a += __shfl_xor(a, off);
      if (l == 0) {
        float sc = b2g[o] / sqrtf(b2v[o] + EPSC);
        h2s[o] = fmaxf((a - b2m[o]) * sc + b2b[o], 0.f);
      }
    }
  }
  __syncthreads();
  // ---- layer 3: [2,64] ----
  if (w == 0) {
    float hv = h2s[l];
#pragma unroll
    for (int o = 0; o < 2; ++o) {
      float a = hv * g3[o * 64 + l];
#pragma unroll
      for (int off = 1; off < 64; off <<= 1) a += __shfl_xor(a, off);
      if (l == 0) { oGl[b * 2 + o] = a; gls[o] = a; }
    }
  }
  __syncthreads();
  if (t == 0) {
    float lg = gls[1] - gls[0];
    oLogit[b] = lg;
    oProb[b] = 1.0f / (1.0f + expf(-lg));
  }
}

// =======================================================================
// BN'd context -> padded bf16 hi/lo planes cph/cpl[b][p 289][c 768].
// Also zeroes the 64 halo pad positions per batch.
__global__ __launch_bounds__(256) void k_cm2(const float* __restrict__ ctx,
    const float* __restrict__ sg, const float* __restrict__ sb,
    const float* __restrict__ sm, const float* __restrict__ sv,
    const int* __restrict__ li_p,
    ushortT* __restrict__ cph, ushortT* __restrict__ cpl) {
  int id = blockIdx.x * 256 + threadIdx.x;
  if (id < 196608) {           // 32 b * 64 pads * 96 uint4
    int v = id % 96;
    int pi = (id / 96) & 63;
    int bb = id / 6144;
    int p = pi < 17 ? pi
          : pi < 32 ? 17 * (pi - 16)
          : pi < 47 ? 17 * (pi - 31) + 16
          : 272 + (pi - 47);
    size_t off = ((size_t)(bb * 289 + p)) * 768 + v * 8;
    uint4 z = {0u, 0u, 0u, 0u};
    *(uint4*)(cph + off) = z;
    *(uint4*)(cpl + off) = z;
  }
  int wid = id >> 6;
  int lane = threadIdx.x & 63;
  if (wid >= 7200) return;
  int b = wid / 225, s = wid % 225;
  int li = li_p[0]; li = li < 2 ? li : 2; if (li < 0) li = 0;
  int p = (s / 15 + 1) * 17 + (s % 15) + 1;
  size_t obase = ((size_t)(b * 289 + p)) * 768;
#pragma unroll
  for (int j = 0; j < 3; ++j) {
    int d0 = j * 256 + lane * 4;
    float4 x  = *(const float4*)(ctx + (size_t)wid * 768 + d0);
    float4 g4 = *(const float4*)(sg + li * 768 + d0);
    float4 v4 = *(const float4*)(sv + li * 768 + d0);
    float4 m4 = *(const float4*)(sm + li * 768 + d0);
    float4 b4 = *(const float4*)(sb + li * 768 + d0);
    float xv[4] = {x.x, x.y, x.z, x.w};
    float gv[4] = {g4.x, g4.y, g4.z, g4.w};
    float vv[4] = {v4.x, v4.y, v4.z, v4.w};
    float mv_[4] = {m4.x, m4.y, m4.z, m4.w};
    float bv_[4] = {b4.x, b4.y, b4.z, b4.w};
    ushortT hu[4], lu[4];
#pragma unroll
    for (int e = 0; e < 4; ++e) {
      float sc = gv[e] / sqrtf(vv[e] + EPSC);
      float val = (xv[e] - mv_[e]) * sc + bv_[e];
      uintT bits = __float_as_uint(val);
      float lo = val - __uint_as_float(bits & 0xFFFF0000u);
      hu[e] = (ushortT)(bits >> 16);
      lu[e] = (ushortT)(__float_as_uint(lo) >> 16);
    }
    uint2 hp, lp;
    hp.x = (uintT)hu[0] | ((uintT)hu[1] << 16);
    hp.y = (uintT)hu[2] | ((uintT)hu[3] << 16);
    lp.x = (uintT)lu[0] | ((uintT)lu[1] << 16);
    lp.y = (uintT)lu[2] | ((uintT)lu[3] << 16);
    *(uint2*)(cph + obase + d0) = hp;
    *(uint2*)(cpl + obase + d0) = lp;
  }
}

// =======================================================================
// conv1 as MFMA implicit GEMM: grid(band 4, nt 4, b 32).
__global__ __launch_bounds__(256) void k_conv1m(
    const ushortT* __restrict__ cph, const ushortT* __restrict__ cpl,
    const ushortT* __restrict__ wpk,
    const float* __restrict__ bg, const float* __restrict__ bb,
    const float* __restrict__ bm, const float* __restrict__ bv,
    float* __restrict__ outp) {
  constexpr int ROWS = 136;
  constexpr int HSZ = ROWS * 80;
  __shared__ __align__(16) unsigned char sA[2 * HSZ];
  int band = blockIdx.x, nt = blockIdx.y, b = blockIdx.z;
  int t = threadIdx.x, w = t >> 6, l = t & 63;
  int r15 = l & 15, g = l >> 4;
  int sub = band * 4 + w;
  bool mvalid = (sub < 15);
  int p0 = ((band * 64) / 15) * 17;
  int s = sub * 16 + r15; if (s > 224) s = 224;
  int pb = (s / 15) * 17 + (s % 15) - p0;
  f32x4 acc[2];
  acc[0] = (f32x4){0.f, 0.f, 0.f, 0.f};
  acc[1] = (f32x4){0.f, 0.f, 0.f, 0.f};
  const size_t planeB = (size_t)b * 289 * 768;

  for (int ch = 0; ch < 24; ++ch) {
    __syncthreads();
    for (int i = t; i < ROWS * 8; i += 256) {
      int r = i >> 3, half = (i >> 2) & 1, seg = i & 3;
      const ushortT* src = (half ? cpl : cph) + planeB +
          (size_t)(p0 + r) * 768 + ch * 32 + seg * 8;
      uint4 v = *(const uint4*)src;
      *(uint4*)(sA + half * HSZ + r * 80 + seg * 16) = v;
    }
    __syncthreads();
#pragma unroll
    for (int pos = 0; pos < 9; ++pos) {
      const ushortT* wbh = wpk + ((size_t)(pos * 24 + ch)) * 4096;
      const ushortT* wbl = wbh + 884736;
      bf16x8 bh[2], bl[2];
#pragma unroll
      for (int nf = 0; nf < 2; ++nf) {
        int off = (nt * 32 + nf * 16 + r15) * 32 + g * 8;
        bh[nf] = *(const bf16x8*)(wbh + off);
        bl[nf] = *(const bf16x8*)(wbl + off);
      }
      int shift = (pos / 3) * 17 + (pos % 3);
      if (mvalid) {
        int row = pb + shift;
        bf16x8 ah = *(const bf16x8*)(sA + row * 80 + g * 16);
        bf16x8 al = *(const bf16x8*)(sA + HSZ + row * 80 + g * 16);
#pragma unroll
        for (int nf = 0; nf < 2; ++nf) {
          f32x4 c = acc[nf];
          c = __builtin_amdgcn_mfma_f32_16x16x32_bf16(ah, bh[nf], c, 0, 0, 0);
          c = __builtin_amdgcn_mfma_f32_16x16x32_bf16(ah, bl[nf], c, 0, 0, 0);
          c = __builtin_amdgcn_mfma_f32_16x16x32_bf16(al, bh[nf], c, 0, 0, 0);
          acc[nf] = c;
        }
      }
    }
  }
  if (mvalid) {
#pragma unroll
    for (int nf = 0; nf < 2; ++nf) {
      int o = nt * 32 + nf * 16 + r15;
      float sc = bg[o] / sqrtf(bv[o] + EPSC);
      float sh = bb[o] - bm[o] * sc;
#pragma unroll
      for (int j = 0; j < 4; ++j) {
        int srow = sub * 16 + g * 4 + j;
        if (srow < 225) {
          outp[((size_t)(b * 128 + o)) * 225 + srow] =
              fmaxf(acc[nf][j] * sc + sh, 0.f);
        }
      }
    }
  }
}

// =======================================================================
// convT1 + bias -> bf16 hi/lo channel-last padded planes t1h/t1l
// [b][32x32 plane][128]. grid(yp 15, b 32), 256 thr. Also zeroes the 124
// border pad positions per batch.
__global__ __launch_bounds__(256) void k_convT1b(const float* __restrict__ in,
    const float* __restrict__ w, const float* __restrict__ bias,
    ushortT* __restrict__ t1h, ushortT* __restrict__ t1l) {
  __shared__ float sIn[128 * 15];
  int yp = blockIdx.x, b = blockIdx.y;
  int t = threadIdx.x;
  {
    int flat = (b * 15 + yp) * 256 + t;
    if (flat < 63488) {        // 32 b * 124 pads * 16 uint4
      int v = flat & 15;
      int pi = (flat >> 4) % 124;
      int bb = flat / 1984;
      int p = pi < 32 ? pi
            : pi < 62 ? 32 * (pi - 31)
            : pi < 92 ? 32 * (pi - 61) + 31
            : 992 + (pi - 92);
      size_t off = ((size_t)bb * 1024 + p) * 128 + v * 8;
      uint4 z = {0u, 0u, 0u, 0u};
      *(uint4*)(t1h + off) = z;
      *(uint4*)(t1l + off) = z;
    }
  }
  int o = t & 127, i = t >> 7;    // i = deconv row parity
  for (int idx = t; idx < 128 * 15; idx += 256) {
    int c = idx / 15, x = idx % 15;
    sIn[idx] = in[((size_t)(b * 128 + c)) * 225 + yp * 15 + x];
  }
  __syncthreads();
  float acc[30];
#pragma unroll
  for (int k = 0; k < 30; ++k) acc[k] = 0.f;
  for (int c = 0; c < 128; ++c) {
    float2 wv = *(const float2*)&w[(((size_t)c * 128 + o) * 2 + i) * 2];
#pragma unroll
    for (int xx = 0; xx < 15; ++xx) {
      float iv = sIn[c * 15 + xx];
      acc[2 * xx] += wv.x * iv;
      acc[2 * xx + 1] += wv.y * iv;
    }
  }
  float bvv = bias[o];
  size_t rowb = (size_t)b * 1024 + 33 + (size_t)(2 * yp + i) * 32;
#pragma unroll
  for (int k = 0; k < 30; ++k) {
    float val = acc[k] + bvv;
    uintT bits = __float_as_uint(val);
    float lo = val - __uint_as_float(bits & 0xFFFF0000u);
    t1h[(rowb + k) * 128 + o] = (ushortT)(bits >> 16);
    t1l[(rowb + k) * 128 + o] = (ushortT)(__float_as_uint(lo) >> 16);
  }
}

// =======================================================================
// conv2 as MFMA implicit GEMM: grid(band 15, b 32), 256 thr / 4 waves.
__global__ __launch_bounds__(256) void k_conv2m(
    const ushortT* __restrict__ t1h, const ushortT* __restrict__ t1l,
    const ushortT* __restrict__ wpk2,
    const float* __restrict__ bg, const float* __restrict__ bb,
    const float* __restrict__ bm, const float* __restrict__ bv,
    float* __restrict__ outp) {
  constexpr int ROWS = 192;
  constexpr int HSZ = ROWS * 80;             // 15360 B per half
  __shared__ __align__(16) unsigned char sA[2 * HSZ];
  int band = blockIdx.x, b = blockIdx.y;
  int t = threadIdx.x, w = t >> 6, l = t & 63;
  int r15 = l & 15, g = l >> 4;
  int sub = band * 4 + w;
  bool mvalid = (sub * 16 < 900);
  int s = sub * 16 + r15; if (s > 899) s = 899;
  int y = s / 30, x = s % 30;
  int ymin = (band * 64) / 30;
  int p0 = ymin * 32; if (p0 > 832) p0 = 832;
  int pbase = y * 32 + x - p0;
  f32x4 acc[4];
#pragma unroll
  for (int nf = 0; nf < 4; ++nf) acc[nf] = (f32x4){0.f, 0.f, 0.f, 0.f};
  const ushortT* t1hb = t1h + (size_t)b * 1024 * 128;
  const ushortT* t1lb = t1l + (size_t)b * 1024 * 128;

  for (int ch = 0; ch < 4; ++ch) {
    __syncthreads();
    for (int i = t; i < ROWS * 8; i += 256) {
      int r = i >> 3, half = (i >> 2) & 1, seg = i & 3;
      const ushortT* src = (half ? t1lb : t1hb) +
          (size_t)(p0 + r) * 128 + ch * 32 + seg * 8;
      uint4 v = *(const uint4*)src;
      *(uint4*)(sA + half * HSZ + r * 80 + seg * 16) = v;
    }
    __syncthreads();
#pragma unroll
    for (int pos = 0; pos < 9; ++pos) {
      const ushortT* wbh = wpk2 + ((size_t)(pos * 4 + ch)) * 2048;
      const ushortT* wbl = wbh + 73728;
      bf16x8 bh[4], bl[4];
#pragma unroll
      for (int nf = 0; nf < 4; ++nf) {
        int off = (nf * 16 + r15) * 32 + g * 8;
        bh[nf] = *(const bf16x8*)(wbh + off);
        bl[nf] = *(const bf16x8*)(wbl + off);
      }
      int shift = (pos / 3) * 32 + (pos % 3);
      if (mvalid) {
        int row = pbase + shift;
        bf16x8 ah = *(const bf16x8*)(sA + row * 80 + g * 16);
        bf16x8 al = *(const bf16x8*)(sA + HSZ + row * 80 + g * 16);
#pragma unroll
        for (int nf = 0; nf < 4; ++nf) {
          f32x4 c = acc[nf];
          c = __builtin_amdgcn_mfma_f32_16x16x32_bf16(ah, bh[nf], c, 0, 0, 0);
          c = __builtin_amdgcn_mfma_f32_16x16x32_bf16(ah, bl[nf], c, 0, 0, 0);
          c = __builtin_amdgcn_mfma_f32_16x16x32_bf16(al, bh[nf], c, 0, 0, 0);
          acc[nf] = c;
        }
      }
    }
  }
  if (mvalid) {
#pragma unroll
    for (int nf = 0; nf < 4; ++nf) {
      int o = nf * 16 + r15;
      float sc = bg[o] / sqrtf(bv[o] + EPSC);
      float sh = bb[o] - bm[o] * sc;
#pragma unroll
      for (int j = 0; j < 4; ++j) {
        int srow = sub * 16 + g * 4 + j;
        if (srow < 900) {
          outp[((size_t)(b * 64 + o)) * 900 + srow] =
              fmaxf(acc[nf][j] * sc + sh, 0.f);
        }
      }
    }
  }
}

// =======================================================================
// convT2 (k=2,s=2, 30->60) FUSED with the 1x1 conv + softmax: the
// deconv tile (2 rows x 60 cols x 64 ch) is staged in LDS (stride 61,
// conflict-free) and consumed in-block. Removes the 59 MB t2b
// round-trip and one dispatch. grid(yp 30, b 32).
__global__ __launch_bounds__(256) void k_convT2f(const float* __restrict__ in,
    const float* __restrict__ w, const float* __restrict__ bias,
    const float* __restrict__ w3, const float* __restrict__ b3,
    float* __restrict__ low, float* __restrict__ patch) {
  __shared__ float sIn[64 * 30];
  __shared__ float sT[2][64][61];
  int yp = blockIdx.x, b = blockIdx.y;
  int t = threadIdx.x;
  int o = t & 63;
  int grp = t >> 6;          // 0..3
  int i = grp & 1;
  int half = grp >> 1;
  int x0 = half * 15;
  for (int idx = t; idx < 64 * 30; idx += 256) {
    int c = idx / 30, x = idx % 30;
    sIn[idx] = in[((size_t)(b * 64 + c) * 30 + yp) * 30 + x];
  }
  __syncthreads();
  float acc[30];
#pragma unroll
  for (int k = 0; k < 30; ++k) acc[k] = 0.f;
  for (int c = 0; c < 64; ++c) {
    float2 wv = *(const float2*)&w[(((size_t)c * 64 + o) * 2 + i) * 2];
#pragma unroll
    for (int xx = 0; xx < 15; ++xx) {
      float iv = sIn[c * 30 + x0 + xx];
      acc[2 * xx] += wv.x * iv;
      acc[2 * xx + 1] += wv.y * iv;
    }
  }
  float bvv = bias[o];
#pragma unroll
  for (int k = 0; k < 30; ++k) sT[i][o][2 * x0 + k] = acc[k] + bvv;
  __syncthreads();
  if (t < 120) {
    int row = t / 60, col = t % 60;
    float a0 = b3[0], a1 = b3[1];
#pragma unroll 8
    for (int c = 0; c < 64; ++c) {
      float v = sT[row][c][col];
      a0 += v * w3[c];
      a1 += v * w3[64 + c];
    }
    int sp = (2 * yp + row) * 60 + col;
    low[(size_t)b * 7200 + sp] = a0;
    low[(size_t)b * 7200 + 3600 + sp] = a1;
    patch[(size_t)b * 3600 + sp] = 1.0f / (1.0f + expf(a0 - a1));
  }
}

// =======================================================================
__global__ __launch_bounds__(256) void k_resize(const float* __restrict__ low,
                                                float* __restrict__ seg) {
  int idx = blockIdx.x * 256 + threadIdx.x;
  if (idx >= 32 * 2 * 240 * 240) return;
  int X = idx % 240;
  int Y = (idx / 240) % 240;
  int cb = idx / (240 * 240);
  const float* lp = low + (size_t)cb * 3600;
  float sy = (Y + 0.5f) * 0.25f - 0.5f;
  float sx = (X + 0.5f) * 0.25f - 0.5f;
  int y0 = (int)floorf(sy), x0 = (int)floorf(sx);
  float fy = sy - y0, fx = sx - x0;
  int y0c = min(max(y0, 0), 59), y1c = min(max(y0 + 1, 0), 59);
  int x0c = min(max(x0, 0), 59), x1c = min(max(x0 + 1, 0), 59);
  float v00 = lp[y0c * 60 + x0c], v01 = lp[y0c * 60 + x1c];
  float v10 = lp[y1c * 60 + x0c], v11 = lp[y1c * 60 + x1c];
  seg[idx] = (1.f - fy) * ((1.f - fx) * v00 + fx * v01) + fy * ((1.f - fx) * v10 + fx * v11);
}

// =======================================================================
extern "C" void kernel_launch(void* const* d_in, const int* in_sizes, int n_in,
                              void* d_out, int out_size, void* d_ws, size_t ws_size,
                              hipStream_t stream) {
  (void)in_sizes; (void)n_in; (void)out_size; (void)ws_size;
  const float* Q    = (const float*)d_in[0];
  const float* PM   = (const float*)d_in[1];
  const int*   LI   = (const int*)d_in[2];
  const float* SG   = (const float*)d_in[3];
  const float* SB   = (const float*)d_in[4];
  const float* SM   = (const float*)d_in[5];
  const float* SV   = (const float*)d_in[6];
  const float* W1   = (const float*)d_in[7];
  const float* BN1G = (const float*)d_in[8];
  const float* BN1B = (const float*)d_in[9];
  const float* BN1M = (const float*)d_in[10];
  const float* BN1V = (const float*)d_in[11];
  const float* WT1  = (const float*)d_in[12];
  const float* BT1  = (const float*)d_in[13];
  const float* W2   = (const float*)d_in[14];
  const float* BN2G = (const float*)d_in[15];
  const float* BN2B = (const float*)d_in[16];
  const float* BN2M = (const float*)d_in[17];
  const float* BN2V = (const float*)d_in[18];
  const float* WT2  = (const float*)d_in[19];
  const float* BT2  = (const float*)d_in[20];
  const float* W3   = (const float*)d_in[21];
  const float* B3   = (const float*)d_in[22];
  const float* G1   = (const float*)d_in[23];
  const float* GB1G = (const float*)d_in[24];
  const float* GB1B = (const float*)d_in[25];
  const float* GB1M = (const float*)d_in[26];
  const float* GB1V = (const float*)d_in[27];
  const float* G2   = (const float*)d_in[28];
  const float* GB2G = (const float*)d_in[29];
  const float* GB2B = (const float*)d_in[30];
  const float* GB2M = (const float*)d_in[31];
  const float* GB2V = (const float*)d_in[32];
  const float* G3   = (const float*)d_in[33];

  float* out = (float*)d_out;
  float* ws = (float*)d_ws;
  double* ms64  = (double*)(ws + WS_MS64);
  float*  avg   = ws + WS_AVG;
  ushortT* qpk  = (ushortT*)(ws + WS_QPK);
  float4* top2g = (float4*)(ws + WS_TOP2G);
  ushortT* cph  = (ushortT*)(ws + WS_CPH);
  ushortT* cpl  = (ushortT*)(ws + WS_CPL);
  ushortT* wpkp = (ushortT*)(ws + WS_WPK);
  ushortT* wpk2p= (ushortT*)(ws + WS_WPK2);
  ushortT* t1h  = (ushortT*)(ws + WS_T1H);
  ushortT* t1l  = (ushortT*)(ws + WS_T1L);
  float* h1b  = ws + WS_H1;
  float* h2b  = ws + WS_H2;
  float* lowb = ws + WS_LOW;

  k_qpackW<<<3348, 256, 0, stream>>>(Q, W1, W2, qpk, wpkp, wpk2p);
  k_simm<<<dim3(64, 32), 256, 0, stream>>>(qpk, PM, top2g);
  k_refine<<<1800, 256, 0, stream>>>(Q, PM, top2g, out + O_IDX, out + O_RES,
                                     out + O_CTX, out + O_ALN, ms64);
  k_pool<<<dim3(32, 3), 256, 0, stream>>>(out + O_CTX, avg);
  k_head<<<32, 256, 0, stream>>>(out + O_CTX, ms64, avg,
                                 G1, GB1G, GB1B, GB1M, GB1V,
                                 G2, GB2G, GB2B, GB2M, GB2V, G3,
                                 out + O_GL, out + O_LOGIT, out + O_PROB);
  k_cm2<<<1800, 256, 0, stream>>>(out + O_CTX, SG, SB, SM, SV, LI, cph, cpl);
  k_conv1m<<<dim3(4, 4, 32), 256, 0, stream>>>(cph, cpl, wpkp,
                                               BN1G, BN1B, BN1M, BN1V, h1b);
  k_convT1b<<<dim3(15, 32), 256, 0, stream>>>(h1b, WT1, BT1, t1h, t1l);
  k_conv2m<<<dim3(15, 32), 256, 0, stream>>>(t1h, t1l, wpk2p,
                                             BN2G, BN2B, BN2M, BN2V, h2b);
  k_convT2f<<<dim3(30, 32), 256, 0, stream>>>(h2b, WT2, BT2, W3, B3,
                                              lowb, out + O_PATCH);
  k_resize<<<14400, 256, 0, stream>>>(lowb, out + O_SEG);
}

// Round 3
// 568.523 us; speedup vs baseline: 1.1137x; 1.1137x over previous
//
#include <hip/hip_runtime.h>
#include <cmath>

#define EPSC 1e-5f
typedef unsigned short ushortT;
typedef unsigned int uintT;
typedef __attribute__((ext_vector_type(8))) short bf16x8;
typedef __attribute__((ext_vector_type(4))) float f32x4;

// ---------------- output layout (floats) ----------------
constexpr size_t O_SEG   = 0;          // 32*2*240*240 = 3686400
constexpr size_t O_GL    = 3686400;    // 64
constexpr size_t O_LOGIT = 3686464;    // 32
constexpr size_t O_PROB  = 3686496;    // 32
constexpr size_t O_PATCH = 3686528;    // 115200
constexpr size_t O_RES   = 3801728;    // 7200
constexpr size_t O_CTX   = 3808928;    // 5529600
constexpr size_t O_ALN   = 9338528;    // 5529600
constexpr size_t O_IDX   = 14868128;   // 7200

// ---------------- ws layout (float elements) ----------------
constexpr size_t WS_MS64 = 0;                    // 7200 doubles = 14400 floats
constexpr size_t WS_AVG  = 14400;                // 24576
constexpr size_t CB      = 38976;
constexpr size_t WS_QPK  = CB;
constexpr size_t WS_TOP2G= CB + 5898240;
constexpr size_t WS_CPH  = CB;
constexpr size_t WS_CPL  = CB + 3551232;
constexpr size_t WS_WPK  = CB + 7102464;
constexpr size_t WS_H1   = CB + 8000000;
constexpr size_t WS_T1H  = CB;                   // 2,097,152 floats (bf16 x2)
constexpr size_t WS_T1L  = CB + 2097152;
constexpr size_t WS_H2   = CB + 4200000;
constexpr size_t WS_WPK2 = CB + 8950000;
constexpr size_t WS_LOW  = CB;

// =======================================================================
// Pack Q -> bf16 hi in MFMA-fragment order (blocks < 2880), and pack
// W1/W2 -> bf16 hi/lo (blocks >= 2880). Merged to save a dispatch.
// Both branches bit-identical to the separate r1 kernels.
__global__ __launch_bounds__(256) void k_qpackW(const float* __restrict__ Q,
    const float* __restrict__ w1, const float* __restrict__ w2,
    ushortT* __restrict__ qpk, ushortT* __restrict__ wpk,
    ushortT* __restrict__ wpk2) {
  int bid = blockIdx.x;
  if (bid < 2880) {
    int id = bid * 256 + threadIdx.x;
    int r = id & 15;
    int g = (id >> 4) & 3;
    int rest = id >> 6;
    int sub = rest % 15;
    int bkc = rest / 15;
    int kc = bkc % 24, b = bkc / 24;
    if (b >= 32) return;
    int q = sub * 16 + r;
    int k0 = kc * 32 + g * 8;
    float x[8];
    if (q < 225) {
      const float* src = Q + ((size_t)(b * 225 + q)) * 768 + k0;
#pragma unroll
      for (int e = 0; e < 8; ++e) x[e] = src[e];
    } else {
#pragma unroll
      for (int e = 0; e < 8; ++e) x[e] = 0.f;
    }
    uintT hb[8];
#pragma unroll
    for (int e = 0; e < 8; ++e) hb[e] = __float_as_uint(x[e]);
    uint4 hv;
    hv.x = (hb[0] >> 16) | (hb[1] & 0xFFFF0000u);
    hv.y = (hb[2] >> 16) | (hb[3] & 0xFFFF0000u);
    hv.z = (hb[4] >> 16) | (hb[5] & 0xFFFF0000u);
    hv.w = (hb[6] >> 16) | (hb[7] & 0xFFFF0000u);
    size_t base = ((size_t)(b * 24 + kc) * 30 + sub) * 512 + (g * 16 + r) * 8;
    *(uint4*)(qpk + base) = hv;
    return;
  }
  int id = (bid - 2880) * 256 + threadIdx.x;
  if (id < 110592) {
    int ccq = id & 3;
    int o = (id >> 2) & 127;
    int pc = id >> 9;
    ushortT hu[8], lu[8];
#pragma unroll
    for (int e = 0; e < 8; ++e) {
      int c = (pc % 24) * 32 + ccq * 8 + e;
      float x = w1[((size_t)o * 768 + c) * 9 + pc / 24];
      uintT bits = __float_as_uint(x);
      float lo = x - __uint_as_float(bits & 0xFFFF0000u);
      hu[e] = (ushortT)(bits >> 16);
      lu[e] = (ushortT)(__float_as_uint(lo) >> 16);
    }
    uint4 h, lw;
    h.x = (uintT)hu[0] | ((uintT)hu[1] << 16);
    h.y = (uintT)hu[2] | ((uintT)hu[3] << 16);
    h.z = (uintT)hu[4] | ((uintT)hu[5] << 16);
    h.w = (uintT)hu[6] | ((uintT)hu[7] << 16);
    lw.x = (uintT)lu[0] | ((uintT)lu[1] << 16);
    lw.y = (uintT)lu[2] | ((uintT)lu[3] << 16);
    lw.z = (uintT)lu[4] | ((uintT)lu[5] << 16);
    lw.w = (uintT)lu[6] | ((uintT)lu[7] << 16);
    size_t base = (((size_t)pc) * 128 + o) * 32 + ccq * 8;
    *(uint4*)(wpk + base) = h;
    *(uint4*)(wpk + 884736 + base) = lw;
  } else {
    int id2 = id - 110592;
    if (id2 >= 9216) return;
    int ccq = id2 & 3;
    int o = (id2 >> 2) & 63;
    int pc = id2 >> 8;                          // pos*4+ch, 0..35
    int pos = pc >> 2, ch = pc & 3;
    ushortT hu[8], lu[8];
#pragma unroll
    for (int e = 0; e < 8; ++e) {
      int c = ch * 32 + ccq * 8 + e;
      float x = w2[((size_t)o * 128 + c) * 9 + pos];
      uintT bits = __float_as_uint(x);
      float lo = x - __uint_as_float(bits & 0xFFFF0000u);
      hu[e] = (ushortT)(bits >> 16);
      lu[e] = (ushortT)(__float_as_uint(lo) >> 16);
    }
    uint4 h, lw;
    h.x = (uintT)hu[0] | ((uintT)hu[1] << 16);
    h.y = (uintT)hu[2] | ((uintT)hu[3] << 16);
    h.z = (uintT)hu[4] | ((uintT)hu[5] << 16);
    h.w = (uintT)hu[6] | ((uintT)hu[7] << 16);
    lw.x = (uintT)lu[0] | ((uintT)lu[1] << 16);
    lw.y = (uintT)lu[2] | ((uintT)lu[3] << 16);
    lw.z = (uintT)lu[4] | ((uintT)lu[5] << 16);
    lw.w = (uintT)lu[6] | ((uintT)lu[7] << 16);
    size_t base = (((size_t)pc) * 64 + o) * 32 + ccq * 8;
    *(uint4*)(wpk2 + base) = h;
    *(uint4*)(wpk2 + 73728 + base) = lw;
  }
}

// =======================================================================
// MFMA sim scan: hi-only bf16 candidate generation. grid(sp=64, b=32).
__global__ __launch_bounds__(256, 3) void k_simm(const ushortT* __restrict__ qpk,
    const float* __restrict__ PM, float4* __restrict__ top2g) {
  __shared__ ushortT sP[2 * 2048];   // [buf][subs 0-3 hi][512]
  __shared__ float4 smrg[240];
  __shared__ float srp[64];
  int sp = blockIdx.x, b = blockIdx.y;
  int t = threadIdx.x;
  int w = t >> 6, l = t & 63;
  int mq = t >> 3, kq = t & 7;
  const int sub0 = w * 4;
  const ushortT* qB0 = qpk + (size_t)(b * 24) * 30 * 512;

#define LOADQ(KC)                                                             \
  {                                                                           \
    const ushortT* qk = qB0 + (size_t)(KC) * (30 * 512);                      \
    _Pragma("unroll")                                                         \
    for (int ss = 0; ss < 4; ++ss) {                                          \
      int subc = sub0 + ss; if (subc > 14) subc = 14;                         \
      qh[ss] = *(const bf16x8*)(qk + subc * 512 + l * 8);                     \
    }                                                                         \
  }

#define LOADP(PR, KC)                                                         \
  {                                                                           \
    _Pragma("unroll")                                                         \
    for (int pass = 0; pass < 2; ++pass) {                                    \
      int ml = mq + pass * 32;                                                \
      PR[pass] = *(const float4*)(pmBase + (size_t)ml * 768 + (KC) * 32 + kq * 4); \
    }                                                                         \
  }

#define CVTW(PR, BUF)                                                         \
  {                                                                           \
    _Pragma("unroll")                                                         \
    for (int pass = 0; pass < 2; ++pass) {                                    \
      int ml = mq + pass * 32;                                                \
      float4 x = PR[pass];                                                    \
      pn[pass] += x.x * x.x + x.y * x.y + x.z * x.z + x.w * x.w;              \
      uintT a0 = __float_as_uint(x.x), a1 = __float_as_uint(x.y);             \
      uintT a2 = __float_as_uint(x.z), a3 = __float_as_uint(x.w);             \
      uintT h01 = (a0 >> 16) | (a1 & 0xFFFF0000u);                            \
      uintT h23 = (a2 >> 16) | (a3 & 0xFFFF0000u);                            \
      int off = (ml >> 4) * 512 + (kq >> 1) * 128 + (ml & 15) * 8 + (kq & 1) * 4; \
      *(uint2*)(&sP[(BUF) + off]) = make_uint2(h01, h23);                     \
    }                                                                         \
  }

#define MFMAPH(BUF)                                                           \
  {                                                                           \
    bf16x8 bh[4];                                                             \
    _Pragma("unroll")                                                         \
    for (int mm = 0; mm < 4; ++mm)                                            \
      bh[mm] = *(const bf16x8*)&sP[(BUF) + mm * 512 + l * 8];                 \
    _Pragma("unroll")                                                         \
    for (int ss = 0; ss < 4; ++ss) {                                          \
      if (sub0 + ss < 15) {                                                   \
        _Pragma("unroll")                                                     \
        for (int mm = 0; mm < 4; ++mm) {                                      \
          acc[ss][mm] = __builtin_amdgcn_mfma_f32_16x16x32_bf16(              \
              qh[ss], bh[mm], acc[ss][mm], 0, 0, 0);                          \
        }                                                                     \
      }                                                                       \
    }                                                                         \
  }

  f32x4 acc[4][4];
#pragma unroll
  for (int ss = 0; ss < 4; ++ss)
#pragma unroll
    for (int mm = 0; mm < 4; ++mm) acc[ss][mm] = (f32x4){0.f, 0.f, 0.f, 0.f};
  float pn[2] = {0.f, 0.f};
  const int mbase = sp * 64;
  const float* pmBase = PM + ((size_t)b * 4096 + mbase) * 768;

  bf16x8 qh[4];
  float4 pr[2];

  LOADP(pr, 0);
  CVTW(pr, 0);
  __syncthreads();

  for (int kc2 = 0; kc2 < 12; ++kc2) {
    int kc = kc2 * 2;
    LOADQ(kc);
    LOADP(pr, kc + 1);
    MFMAPH(0);
    CVTW(pr, 2048);
    __syncthreads();
    LOADQ(kc + 1);
    if (kc2 < 11) {
      LOADP(pr, kc + 2);
    }
    MFMAPH(2048);
    if (kc2 < 11) {
      CVTW(pr, 0);
    }
    __syncthreads();
  }

#pragma unroll
  for (int pass = 0; pass < 2; ++pass) {
    float v = pn[pass];
    v += __shfl_xor(v, 1); v += __shfl_xor(v, 2); v += __shfl_xor(v, 4);
    if (kq == 0) srp[mq + pass * 32] = 1.0f / fmaxf(sqrtf(v), 1e-12f);
  }
  __syncthreads();
  float rpv_[4];
#pragma unroll
  for (int mf = 0; mf < 4; ++mf) rpv_[mf] = srp[mf * 16 + (l & 15)];
#pragma unroll
  for (int ss = 0; ss < 4; ++ss) {
    int sub = sub0 + ss;
    if (sub >= 15) break;
#pragma unroll
    for (int j = 0; j < 4; ++j) {
      float a1 = -1e30f, a2 = -1e30f; int ai1 = -1, ai2 = -1;
#pragma unroll
      for (int mf = 0; mf < 4; ++mf) {
        float v = acc[ss][mf][j] * rpv_[mf];
        int mi = mbase + mf * 16 + (l & 15);
        if (v > a1) { a2 = a1; ai2 = ai1; a1 = v; ai1 = mi; }
        else if (v > a2) { a2 = v; ai2 = mi; }
      }
#pragma unroll
      for (int o = 1; o <= 8; o <<= 1) {
        float b1 = __shfl_xor(a1, o), b2 = __shfl_xor(a2, o);
        int bi1 = __shfl_xor(ai1, o), bi2 = __shfl_xor(ai2, o);
        if (b1 > a1) {
          float n2; int ni2;
          if (a1 > b2) { n2 = a1; ni2 = ai1; } else { n2 = b2; ni2 = bi2; }
          a1 = b1; ai1 = bi1; a2 = n2; ai2 = ni2;
        } else {
          if (b1 > a2) { a2 = b1; ai2 = bi1; }
        }
      }
      if ((l & 15) == j) {
        int row = sub * 16 + (l >> 4) * 4 + j;
        smrg[row] = make_float4(a1, a2, __int_as_float(ai1), __int_as_float(ai2));
      }
    }
  }
  __syncthreads();
  if (t < 240) top2g[((size_t)(b * 240 + t)) * 64 + sp] = smrg[t];
#undef LOADQ
#undef LOADP
#undef CVTW
#undef MFMAPH
}

// =======================================================================
// refine: gather 128 candidates, approx-top8, f64 rescore (batched 2x4
// for ILP). Arithmetic order per candidate is bit-identical to serial.
__global__ __launch_bounds__(256) void k_refine(const float* __restrict__ Q,
    const float* __restrict__ PM, const float4* __restrict__ top2g,
    float* __restrict__ oIdx, float* __restrict__ oRes,
    float* __restrict__ oCtx, float* __restrict__ oAln,
    double* __restrict__ ms64) {
  int wid = (blockIdx.x * 256 + threadIdx.x) >> 6;
  int lane = threadIdx.x & 63;
  if (wid >= 7200) return;
  int b = wid / 225, pr = wid % 225;
  float4 e = top2g[((size_t)(b * 240 + pr)) * 64 + lane];
  float v1 = e.x, v2 = e.y;
  int i1 = __float_as_int(e.z), i2 = __float_as_int(e.w);
  int cand[8];
#pragma unroll
  for (int k = 0; k < 8; ++k) {
    float v = v1; int mi = i1;
    if (v2 > v || (v2 == v && (uintT)i2 < (uintT)mi)) { v = v2; mi = i2; }
#pragma unroll
    for (int o = 1; o <= 32; o <<= 1) {
      float ov = __shfl_xor(v, o); int omi = __shfl_xor(mi, o);
      if (ov > v || (ov == v && (uintT)omi < (uintT)mi)) { v = ov; mi = omi; }
    }
    cand[k] = mi;
    if (i1 == mi) v1 = -3e38f;
    if (i2 == mi) v2 = -3e38f;
  }
  const float* qr = Q + ((size_t)b * 225 + pr) * 768;
  float qv[12]; double nq = 0.0;
#pragma unroll
  for (int j = 0; j < 12; ++j) { float x = qr[lane + 64 * j]; qv[j] = x; nq += (double)x * (double)x; }
#pragma unroll
  for (int o = 1; o < 64; o <<= 1) nq += __shfl_xor(nq, o);
  double qn = fmax(sqrt(nq), 1e-12);
  double best = -1e300; int bi = 0;
#pragma unroll
  for (int pass = 0; pass < 2; ++pass) {
    const float* pp[4];
    double d[4], nn[4];
#pragma unroll
    for (int c = 0; c < 4; ++c) {
      pp[c] = PM + ((size_t)b * 4096 + cand[pass * 4 + c]) * 768 + lane;
      d[c] = 0.0; nn[c] = 0.0;
    }
#pragma unroll
    for (int j = 0; j < 12; ++j) {
#pragma unroll
      for (int c = 0; c < 4; ++c) {
        double pe = (double)pp[c][64 * j];
        d[c] += (double)qv[j] * pe;
        nn[c] += pe * pe;
      }
    }
#pragma unroll
    for (int o = 1; o < 64; o <<= 1) {
#pragma unroll
      for (int c = 0; c < 4; ++c) {
        d[c] += __shfl_xor(d[c], o);
        nn[c] += __shfl_xor(nn[c], o);
      }
    }
#pragma unroll
    for (int c = 0; c < 4; ++c) {
      int mi = cand[pass * 4 + c];
      double s = d[c] / (qn * fmax(sqrt(nn[c]), 1e-12));
      if (s > best || (s == best && mi < bi)) { best = s; bi = mi; }
    }
  }
  if (lane == 0) {
    oIdx[wid] = (float)bi;
    oRes[wid] = (float)(0.5 * (1.0 - best));
    ms64[wid] = best;
  }
  const float* ar = PM + ((size_t)b * 4096 + bi) * 768;
  float* cw = oCtx + (size_t)wid * 768;
  float* aw = oAln + (size_t)wid * 768;
#pragma unroll
  for (int j = 0; j < 12; ++j) {
    float a = ar[lane + 64 * j];
    float qq = qv[j];
    aw[lane + 64 * j] = a;
    cw[lane + 64 * j] = qq + fabsf(qq - a);
  }
}

// =======================================================================
__global__ __launch_bounds__(256) void k_pool(const float* __restrict__ ctx,
                                              float* __restrict__ avg) {
  int b = blockIdx.x, c = blockIdx.y, t = threadIdx.x;
  int d = c * 256 + t;
  float s = 0.f;
  for (int p = 0; p < 225; ++p) s += ctx[((size_t)b * 225 + p) * 768 + d];
  avg[b * 768 + d] = s / 225.0f;
}

// =======================================================================
// global head (r1 version, serial summation order — accuracy-validated;
// the butterfly rewrite amplified reduction-order error through 3 layers
// to absmax 0.017).
__global__ __launch_bounds__(256) void k_head(const float* __restrict__ ctx,
    const double* __restrict__ ms64, const float* __restrict__ avg,
    const float* __restrict__ g1, const float* __restrict__ b1g, const float* __restrict__ b1b,
    const float* __restrict__ b1m, const float* __restrict__ b1v,
    const float* __restrict__ g2, const float* __restrict__ b2g, const float* __restrict__ b2b,
    const float* __restrict__ b2m, const float* __restrict__ b2v,
    const float* __restrict__ g3,
    float* __restrict__ oGl, float* __restrict__ oLogit, float* __restrict__ oProb) {
  __shared__ int tki[10];
  __shared__ float pooled[768];
  __shared__ float h1s[128];
  __shared__ float h2s[64];
  __shared__ float gls[2];
  int b = blockIdx.x, t = threadIdx.x;
  if (t < 64) {
    double rv[4]; int ri[4];
#pragma unroll
    for (int j = 0; j < 4; ++j) {
      int p = t + 64 * j; ri[j] = p;
      rv[j] = (p < 225) ? 0.5 * (1.0 - ms64[b * 225 + p]) : -1e300;
    }
    for (int k = 0; k < 10; ++k) {
      double bv = -1e301; int bI = 1 << 30;
#pragma unroll
      for (int j = 0; j < 4; ++j)
        if (rv[j] > bv || (rv[j] == bv && ri[j] < bI)) { bv = rv[j]; bI = ri[j]; }
#pragma unroll
      for (int o = 1; o < 64; o <<= 1) {
        double ov = __shfl_xor(bv, o); int oi = __shfl_xor(bI, o);
        if (ov > bv || (ov == bv && oi < bI)) { bv = ov; bI = oi; }
      }
      if (t == 0) tki[k] = bI;
#pragma unroll
      for (int j = 0; j < 4; ++j) if (ri[j] == bI) rv[j] = -1e300;
    }
  }
  __syncthreads();
#pragma unroll
  for (int di = 0; di < 3; ++di) {
    int d = t + di * 256;
    float s = 0.f;
    for (int k = 0; k < 10; ++k) s += ctx[((size_t)b * 225 + tki[k]) * 768 + d];
    pooled[d] = 0.5f * avg[b * 768 + d] + 0.5f * (s / 10.0f);
  }
  __syncthreads();
  if (t < 128) {
    float a = 0.f;
    for (int k = 0; k < 768; ++k) a += pooled[k] * g1[t * 768 + k];
    float sc = b1g[t] / sqrtf(b1v[t] + EPSC);
    h1s[t] = fmaxf((a - b1m[t]) * sc + b1b[t], 0.f);
  }
  __syncthreads();
  if (t < 64) {
    float a = 0.f;
    for (int k = 0; k < 128; ++k) a += h1s[k] * g2[t * 128 + k];
    float sc = b2g[t] / sqrtf(b2v[t] + EPSC);
    h2s[t] = fmaxf((a - b2m[t]) * sc + b2b[t], 0.f);
  }
  __syncthreads();
  if (t < 2) {
    float a = 0.f;
    for (int k = 0; k < 64; ++k) a += h2s[k] * g3[t * 64 + k];
    oGl[b * 2 + t] = a;
    gls[t] = a;
  }
  __syncthreads();
  if (t == 0) {
    float lg = gls[1] - gls[0];
    oLogit[b] = lg;
    oProb[b] = 1.0f / (1.0f + expf(-lg));
  }
}

// =======================================================================
// BN'd context -> padded bf16 hi/lo planes cph/cpl[b][p 289][c 768].
// Also zeroes the 64 halo pad positions per batch.
__global__ __launch_bounds__(256) void k_cm2(const float* __restrict__ ctx,
    const float* __restrict__ sg, const float* __restrict__ sb,
    const float* __restrict__ sm, const float* __restrict__ sv,
    const int* __restrict__ li_p,
    ushortT* __restrict__ cph, ushortT* __restrict__ cpl) {
  int id = blockIdx.x * 256 + threadIdx.x;
  if (id < 196608) {           // 32 b * 64 pads * 96 uint4
    int v = id % 96;
    int pi = (id / 96) & 63;
    int bb = id / 6144;
    int p = pi < 17 ? pi
          : pi < 32 ? 17 * (pi - 16)
          : pi < 47 ? 17 * (pi - 31) + 16
          : 272 + (pi - 47);
    size_t off = ((size_t)(bb * 289 + p)) * 768 + v * 8;
    uint4 z = {0u, 0u, 0u, 0u};
    *(uint4*)(cph + off) = z;
    *(uint4*)(cpl + off) = z;
  }
  int wid = id >> 6;
  int lane = threadIdx.x & 63;
  if (wid >= 7200) return;
  int b = wid / 225, s = wid % 225;
  int li = li_p[0]; li = li < 2 ? li : 2; if (li < 0) li = 0;
  int p = (s / 15 + 1) * 17 + (s % 15) + 1;
  size_t obase = ((size_t)(b * 289 + p)) * 768;
#pragma unroll
  for (int j = 0; j < 3; ++j) {
    int d0 = j * 256 + lane * 4;
    float4 x  = *(const float4*)(ctx + (size_t)wid * 768 + d0);
    float4 g4 = *(const float4*)(sg + li * 768 + d0);
    float4 v4 = *(const float4*)(sv + li * 768 + d0);
    float4 m4 = *(const float4*)(sm + li * 768 + d0);
    float4 b4 = *(const float4*)(sb + li * 768 + d0);
    float xv[4] = {x.x, x.y, x.z, x.w};
    float gv[4] = {g4.x, g4.y, g4.z, g4.w};
    float vv[4] = {v4.x, v4.y, v4.z, v4.w};
    float mv_[4] = {m4.x, m4.y, m4.z, m4.w};
    float bv_[4] = {b4.x, b4.y, b4.z, b4.w};
    ushortT hu[4], lu[4];
#pragma unroll
    for (int e = 0; e < 4; ++e) {
      float sc = gv[e] / sqrtf(vv[e] + EPSC);
      float val = (xv[e] - mv_[e]) * sc + bv_[e];
      uintT bits = __float_as_uint(val);
      float lo = val - __uint_as_float(bits & 0xFFFF0000u);
      hu[e] = (ushortT)(bits >> 16);
      lu[e] = (ushortT)(__float_as_uint(lo) >> 16);
    }
    uint2 hp, lp;
    hp.x = (uintT)hu[0] | ((uintT)hu[1] << 16);
    hp.y = (uintT)hu[2] | ((uintT)hu[3] << 16);
    lp.x = (uintT)lu[0] | ((uintT)lu[1] << 16);
    lp.y = (uintT)lu[2] | ((uintT)lu[3] << 16);
    *(uint2*)(cph + obase + d0) = hp;
    *(uint2*)(cpl + obase + d0) = lp;
  }
}

// =======================================================================
// conv1 as MFMA implicit GEMM: grid(band 4, nt 4, b 32).
__global__ __launch_bounds__(256) void k_conv1m(
    const ushortT* __restrict__ cph, const ushortT* __restrict__ cpl,
    const ushortT* __restrict__ wpk,
    const float* __restrict__ bg, const float* __restrict__ bb,
    const float* __restrict__ bm, const float* __restrict__ bv,
    float* __restrict__ outp) {
  constexpr int ROWS = 136;
  constexpr int HSZ = ROWS * 80;
  __shared__ __align__(16) unsigned char sA[2 * HSZ];
  int band = blockIdx.x, nt = blockIdx.y, b = blockIdx.z;
  int t = threadIdx.x, w = t >> 6, l = t & 63;
  int r15 = l & 15, g = l >> 4;
  int sub = band * 4 + w;
  bool mvalid = (sub < 15);
  int p0 = ((band * 64) / 15) * 17;
  int s = sub * 16 + r15; if (s > 224) s = 224;
  int pb = (s / 15) * 17 + (s % 15) - p0;
  f32x4 acc[2];
  acc[0] = (f32x4){0.f, 0.f, 0.f, 0.f};
  acc[1] = (f32x4){0.f, 0.f, 0.f, 0.f};
  const size_t planeB = (size_t)b * 289 * 768;

  for (int ch = 0; ch < 24; ++ch) {
    __syncthreads();
    for (int i = t; i < ROWS * 8; i += 256) {
      int r = i >> 3, half = (i >> 2) & 1, seg = i & 3;
      const ushortT* src = (half ? cpl : cph) + planeB +
          (size_t)(p0 + r) * 768 + ch * 32 + seg * 8;
      uint4 v = *(const uint4*)src;
      *(uint4*)(sA + half * HSZ + r * 80 + seg * 16) = v;
    }
    __syncthreads();
#pragma unroll
    for (int pos = 0; pos < 9; ++pos) {
      const ushortT* wbh = wpk + ((size_t)(pos * 24 + ch)) * 4096;
      const ushortT* wbl = wbh + 884736;
      bf16x8 bh[2], bl[2];
#pragma unroll
      for (int nf = 0; nf < 2; ++nf) {
        int off = (nt * 32 + nf * 16 + r15) * 32 + g * 8;
        bh[nf] = *(const bf16x8*)(wbh + off);
        bl[nf] = *(const bf16x8*)(wbl + off);
      }
      int shift = (pos / 3) * 17 + (pos % 3);
      if (mvalid) {
        int row = pb + shift;
        bf16x8 ah = *(const bf16x8*)(sA + row * 80 + g * 16);
        bf16x8 al = *(const bf16x8*)(sA + HSZ + row * 80 + g * 16);
#pragma unroll
        for (int nf = 0; nf < 2; ++nf) {
          f32x4 c = acc[nf];
          c = __builtin_amdgcn_mfma_f32_16x16x32_bf16(ah, bh[nf], c, 0, 0, 0);
          c = __builtin_amdgcn_mfma_f32_16x16x32_bf16(ah, bl[nf], c, 0, 0, 0);
          c = __builtin_amdgcn_mfma_f32_16x16x32_bf16(al, bh[nf], c, 0, 0, 0);
          acc[nf] = c;
        }
      }
    }
  }
  if (mvalid) {
#pragma unroll
    for (int nf = 0; nf < 2; ++nf) {
      int o = nt * 32 + nf * 16 + r15;
      float sc = bg[o] / sqrtf(bv[o] + EPSC);
      float sh = bb[o] - bm[o] * sc;
#pragma unroll
      for (int j = 0; j < 4; ++j) {
        int srow = sub * 16 + g * 4 + j;
        if (srow < 225) {
          outp[((size_t)(b * 128 + o)) * 225 + srow] =
              fmaxf(acc[nf][j] * sc + sh, 0.f);
        }
      }
    }
  }
}

// =======================================================================
// convT1 + bias -> bf16 hi/lo channel-last padded planes t1h/t1l
// [b][32x32 plane][128]. grid(yp 15, b 32), 256 thr. Also zeroes the 124
// border pad positions per batch.
__global__ __launch_bounds__(256) void k_convT1b(const float* __restrict__ in,
    const float* __restrict__ w, const float* __restrict__ bias,
    ushortT* __restrict__ t1h, ushortT* __restrict__ t1l) {
  __shared__ float sIn[128 * 15];
  int yp = blockIdx.x, b = blockIdx.y;
  int t = threadIdx.x;
  {
    int flat = (b * 15 + yp) * 256 + t;
    if (flat < 63488) {        // 32 b * 124 pads * 16 uint4
      int v = flat & 15;
      int pi = (flat >> 4) % 124;
      int bb = flat / 1984;
      int p = pi < 32 ? pi
            : pi < 62 ? 32 * (pi - 31)
            : pi < 92 ? 32 * (pi - 61) + 31
            : 992 + (pi - 92);
      size_t off = ((size_t)bb * 1024 + p) * 128 + v * 8;
      uint4 z = {0u, 0u, 0u, 0u};
      *(uint4*)(t1h + off) = z;
      *(uint4*)(t1l + off) = z;
    }
  }
  int o = t & 127, i = t >> 7;    // i = deconv row parity
  for (int idx = t; idx < 128 * 15; idx += 256) {
    int c = idx / 15, x = idx % 15;
    sIn[idx] = in[((size_t)(b * 128 + c)) * 225 + yp * 15 + x];
  }
  __syncthreads();
  float acc[30];
#pragma unroll
  for (int k = 0; k < 30; ++k) acc[k] = 0.f;
  for (int c = 0; c < 128; ++c) {
    float2 wv = *(const float2*)&w[(((size_t)c * 128 + o) * 2 + i) * 2];
#pragma unroll
    for (int xx = 0; xx < 15; ++xx) {
      float iv = sIn[c * 15 + xx];
      acc[2 * xx] += wv.x * iv;
      acc[2 * xx + 1] += wv.y * iv;
    }
  }
  float bvv = bias[o];
  size_t rowb = (size_t)b * 1024 + 33 + (size_t)(2 * yp + i) * 32;
#pragma unroll
  for (int k = 0; k < 30; ++k) {
    float val = acc[k] + bvv;
    uintT bits = __float_as_uint(val);
    float lo = val - __uint_as_float(bits & 0xFFFF0000u);
    t1h[(rowb + k) * 128 + o] = (ushortT)(bits >> 16);
    t1l[(rowb + k) * 128 + o] = (ushortT)(__float_as_uint(lo) >> 16);
  }
}

// =======================================================================
// conv2 as MFMA implicit GEMM: grid(band 15, b 32), 256 thr / 4 waves.
__global__ __launch_bounds__(256) void k_conv2m(
    const ushortT* __restrict__ t1h, const ushortT* __restrict__ t1l,
    const ushortT* __restrict__ wpk2,
    const float* __restrict__ bg, const float* __restrict__ bb,
    const float* __restrict__ bm, const float* __restrict__ bv,
    float* __restrict__ outp) {
  constexpr int ROWS = 192;
  constexpr int HSZ = ROWS * 80;             // 15360 B per half
  __shared__ __align__(16) unsigned char sA[2 * HSZ];
  int band = blockIdx.x, b = blockIdx.y;
  int t = threadIdx.x, w = t >> 6, l = t & 63;
  int r15 = l & 15, g = l >> 4;
  int sub = band * 4 + w;
  bool mvalid = (sub * 16 < 900);
  int s = sub * 16 + r15; if (s > 899) s = 899;
  int y = s / 30, x = s % 30;
  int ymin = (band * 64) / 30;
  int p0 = ymin * 32; if (p0 > 832) p0 = 832;
  int pbase = y * 32 + x - p0;
  f32x4 acc[4];
#pragma unroll
  for (int nf = 0; nf < 4; ++nf) acc[nf] = (f32x4){0.f, 0.f, 0.f, 0.f};
  const ushortT* t1hb = t1h + (size_t)b * 1024 * 128;
  const ushortT* t1lb = t1l + (size_t)b * 1024 * 128;

  for (int ch = 0; ch < 4; ++ch) {
    __syncthreads();
    for (int i = t; i < ROWS * 8; i += 256) {
      int r = i >> 3, half = (i >> 2) & 1, seg = i & 3;
      const ushortT* src = (half ? t1lb : t1hb) +
          (size_t)(p0 + r) * 128 + ch * 32 + seg * 8;
      uint4 v = *(const uint4*)src;
      *(uint4*)(sA + half * HSZ + r * 80 + seg * 16) = v;
    }
    __syncthreads();
#pragma unroll
    for (int pos = 0; pos < 9; ++pos) {
      const ushortT* wbh = wpk2 + ((size_t)(pos * 4 + ch)) * 2048;
      const ushortT* wbl = wbh + 73728;
      bf16x8 bh[4], bl[4];
#pragma unroll
      for (int nf = 0; nf < 4; ++nf) {
        int off = (nf * 16 + r15) * 32 + g * 8;
        bh[nf] = *(const bf16x8*)(wbh + off);
        bl[nf] = *(const bf16x8*)(wbl + off);
      }
      int shift = (pos / 3) * 32 + (pos % 3);
      if (mvalid) {
        int row = pbase + shift;
        bf16x8 ah = *(const bf16x8*)(sA + row * 80 + g * 16);
        bf16x8 al = *(const bf16x8*)(sA + HSZ + row * 80 + g * 16);
#pragma unroll
        for (int nf = 0; nf < 4; ++nf) {
          f32x4 c = acc[nf];
          c = __builtin_amdgcn_mfma_f32_16x16x32_bf16(ah, bh[nf], c, 0, 0, 0);
          c = __builtin_amdgcn_mfma_f32_16x16x32_bf16(ah, bl[nf], c, 0, 0, 0);
          c = __builtin_amdgcn_mfma_f32_16x16x32_bf16(al, bh[nf], c, 0, 0, 0);
          acc[nf] = c;
        }
      }
    }
  }
  if (mvalid) {
#pragma unroll
    for (int nf = 0; nf < 4; ++nf) {
      int o = nf * 16 + r15;
      float sc = bg[o] / sqrtf(bv[o] + EPSC);
      float sh = bb[o] - bm[o] * sc;
#pragma unroll
      for (int j = 0; j < 4; ++j) {
        int srow = sub * 16 + g * 4 + j;
        if (srow < 900) {
          outp[((size_t)(b * 64 + o)) * 900 + srow] =
              fmaxf(acc[nf][j] * sc + sh, 0.f);
        }
      }
    }
  }
}

// =======================================================================
// convT2 (k=2,s=2, 30->60) FUSED with the 1x1 conv + softmax: the
// deconv tile (2 rows x 60 cols x 64 ch) is staged in LDS (stride 61,
// conflict-free) and consumed in-block. Bit-identical arithmetic to the
// separate k_convT + k_conv1x1 path. grid(yp 30, b 32).
__global__ __launch_bounds__(256) void k_convT2f(const float* __restrict__ in,
    const float* __restrict__ w, const float* __restrict__ bias,
    const float* __restrict__ w3, const float* __restrict__ b3,
    float* __restrict__ low, float* __restrict__ patch) {
  __shared__ float sIn[64 * 30];
  __shared__ float sT[2][64][61];
  int yp = blockIdx.x, b = blockIdx.y;
  int t = threadIdx.x;
  int o = t & 63;
  int grp = t >> 6;          // 0..3
  int i = grp & 1;
  int half = grp >> 1;
  int x0 = half * 15;
  for (int idx = t; idx < 64 * 30; idx += 256) {
    int c = idx / 30, x = idx % 30;
    sIn[idx] = in[((size_t)(b * 64 + c) * 30 + yp) * 30 + x];
  }
  __syncthreads();
  float acc[30];
#pragma unroll
  for (int k = 0; k < 30; ++k) acc[k] = 0.f;
  for (int c = 0; c < 64; ++c) {
    float2 wv = *(const float2*)&w[(((size_t)c * 64 + o) * 2 + i) * 2];
#pragma unroll
    for (int xx = 0; xx < 15; ++xx) {
      float iv = sIn[c * 30 + x0 + xx];
      acc[2 * xx] += wv.x * iv;
      acc[2 * xx + 1] += wv.y * iv;
    }
  }
  float bvv = bias[o];
#pragma unroll
  for (int k = 0; k < 30; ++k) sT[i][o][2 * x0 + k] = acc[k] + bvv;
  __syncthreads();
  if (t < 120) {
    int row = t / 60, col = t % 60;
    float a0 = b3[0], a1 = b3[1];
#pragma unroll 8
    for (int c = 0; c < 64; ++c) {
      float v = sT[row][c][col];
      a0 += v * w3[c];
      a1 += v * w3[64 + c];
    }
    int sp = (2 * yp + row) * 60 + col;
    low[(size_t)b * 7200 + sp] = a0;
    low[(size_t)b * 7200 + 3600 + sp] = a1;
    patch[(size_t)b * 3600 + sp] = 1.0f / (1.0f + expf(a0 - a1));
  }
}

// =======================================================================
__global__ __launch_bounds__(256) void k_resize(const float* __restrict__ low,
                                                float* __restrict__ seg) {
  int idx = blockIdx.x * 256 + threadIdx.x;
  if (idx >= 32 * 2 * 240 * 240) return;
  int X = idx % 240;
  int Y = (idx / 240) % 240;
  int cb = idx / (240 * 240);
  const float* lp = low + (size_t)cb * 3600;
  float sy = (Y + 0.5f) * 0.25f - 0.5f;
  float sx = (X + 0.5f) * 0.25f - 0.5f;
  int y0 = (int)floorf(sy), x0 = (int)floorf(sx);
  float fy = sy - y0, fx = sx - x0;
  int y0c = min(max(y0, 0), 59), y1c = min(max(y0 + 1, 0), 59);
  int x0c = min(max(x0, 0), 59), x1c = min(max(x0 + 1, 0), 59);
  float v00 = lp[y0c * 60 + x0c], v01 = lp[y0c * 60 + x1c];
  float v10 = lp[y1c * 60 + x0c], v11 = lp[y1c * 60 + x1c];
  seg[idx] = (1.f - fy) * ((1.f - fx) * v00 + fx * v01) + fy * ((1.f - fx) * v10 + fx * v11);
}

// =======================================================================
extern "C" void kernel_launch(void* const* d_in, const int* in_sizes, int n_in,
                              void* d_out, int out_size, void* d_ws, size_t ws_size,
                              hipStream_t stream) {
  (void)in_sizes; (void)n_in; (void)out_size; (void)ws_size;
  const float* Q    = (const float*)d_in[0];
  const float* PM   = (const float*)d_in[1];
  const int*   LI   = (const int*)d_in[2];
  const float* SG   = (const float*)d_in[3];
  const float* SB   = (const float*)d_in[4];
  const float* SM   = (const float*)d_in[5];
  const float* SV   = (const float*)d_in[6];
  const float* W1   = (const float*)d_in[7];
  const float* BN1G = (const float*)d_in[8];
  const float* BN1B = (const float*)d_in[9];
  const float* BN1M = (const float*)d_in[10];
  const float* BN1V = (const float*)d_in[11];
  const float* WT1  = (const float*)d_in[12];
  const float* BT1  = (const float*)d_in[13];
  const float* W2   = (const float*)d_in[14];
  const float* BN2G = (const float*)d_in[15];
  const float* BN2B = (const float*)d_in[16];
  const float* BN2M = (const float*)d_in[17];
  const float* BN2V = (const float*)d_in[18];
  const float* WT2  = (const float*)d_in[19];
  const float* BT2  = (const float*)d_in[20];
  const float* W3   = (const float*)d_in[21];
  const float* B3   = (const float*)d_in[22];
  const float* G1   = (const float*)d_in[23];
  const float* GB1G = (const float*)d_in[24];
  const float* GB1B = (const float*)d_in[25];
  const float* GB1M = (const float*)d_in[26];
  const float* GB1V = (const float*)d_in[27];
  const float* G2   = (const float*)d_in[28];
  const float* GB2G = (const float*)d_in[29];
  const float* GB2B = (const float*)d_in[30];
  const float* GB2M = (const float*)d_in[31];
  const float* GB2V = (const float*)d_in[32];
  const float* G3   = (const float*)d_in[33];

  float* out = (float*)d_out;
  float* ws = (float*)d_ws;
  double* ms64  = (double*)(ws + WS_MS64);
  float*  avg   = ws + WS_AVG;
  ushortT* qpk  = (ushortT*)(ws + WS_QPK);
  float4* top2g = (float4*)(ws + WS_TOP2G);
  ushortT* cph  = (ushortT*)(ws + WS_CPH);
  ushortT* cpl  = (ushortT*)(ws + WS_CPL);
  ushortT* wpkp = (ushortT*)(ws + WS_WPK);
  ushortT* wpk2p= (ushortT*)(ws + WS_WPK2);
  ushortT* t1h  = (ushortT*)(ws + WS_T1H);
  ushortT* t1l  = (ushortT*)(ws + WS_T1L);
  float* h1b  = ws + WS_H1;
  float* h2b  = ws + WS_H2;
  float* lowb = ws + WS_LOW;

  k_qpackW<<<3348, 256, 0, stream>>>(Q, W1, W2, qpk, wpkp, wpk2p);
  k_simm<<<dim3(64, 32), 256, 0, stream>>>(qpk, PM, top2g);
  k_refine<<<1800, 256, 0, stream>>>(Q, PM, top2g, out + O_IDX, out + O_RES,
                                     out + O_CTX, out + O_ALN, ms64);
  k_pool<<<dim3(32, 3), 256, 0, stream>>>(out + O_CTX, avg);
  k_head<<<32, 256, 0, stream>>>(out + O_CTX, ms64, avg,
                                 G1, GB1G, GB1B, GB1M, GB1V,
                                 G2, GB2G, GB2B, GB2M, GB2V, G3,
                                 out + O_GL, out + O_LOGIT, out + O_PROB);
  k_cm2<<<1800, 256, 0, stream>>>(out + O_CTX, SG, SB, SM, SV, LI, cph, cpl);
  k_conv1m<<<dim3(4, 4, 32), 256, 0, stream>>>(cph, cpl, wpkp,
                                               BN1G, BN1B, BN1M, BN1V, h1b);
  k_convT1b<<<dim3(15, 32), 256, 0, stream>>>(h1b, WT1, BT1, t1h, t1l);
  k_conv2m<<<dim3(15, 32), 256, 0, stream>>>(t1h, t1l, wpk2p,
                                             BN2G, BN2B, BN2M, BN2V, h2b);
  k_convT2f<<<dim3(30, 32), 256, 0, stream>>>(h2b, WT2, BT2, W3, B3,
                                              lowb, out + O_PATCH);
  k_resize<<<14400, 256, 0, stream>>>(lowb, out + O_SEG);
}